// Round 10
// baseline (258.300 us; speedup 1.0000x reference)
//
#include <hip/hip_runtime.h>

#define NN 100000
#define NE 1600000
#define ENT (NE + NN)      // edges + self loops
#define NB 196             // bins of 512 dst nodes (dst >> 9)
#define BINCAP 10240       // slab capacity per bin (mean 8192+512, +17 sigma)

typedef float f4v __attribute__((ext_vector_type(4)));   // NT-builtin-compatible

// ---------------- collapsed weights step 1 + (block 0) probe/zero setup ----------------
// T2[j][k] = sum_q W1[q][k] * W2[j][q]      (T = W1^T W2^T, stored transposed [64][128])
// lane-varying index k is contiguous in all vector accesses; j is wave-uniform.

__global__ __launch_bounds__(256) void wprod1_kernel(const float* __restrict__ W1,
                                                     const float* __restrict__ W2,
                                                     float* __restrict__ T2,
                                                     const unsigned* __restrict__ edges,
                                                     int* __restrict__ flag,
                                                     int* __restrict__ binCnt) {
    if (blockIdx.x == 0) {                 // fused setup
        int t = threadIdx.x;
        if (t < NB) binCnt[t] = 0;
        if (t == 0) {
            int is64 = 1;
            for (int i = 1; i < 64; i += 2)
                if (edges[i] != 0u) { is64 = 0; break; }
            *flag = is64;
        }
    }
    int idx = blockIdx.x * blockDim.x + threadIdx.x;   // [0, 8192)
    int k = idx & 127;            // lane-contiguous
    int j = idx >> 7;             // wave-uniform
    float s0 = 0.f, s1 = 0.f, s2 = 0.f, s3 = 0.f;
    #pragma unroll 4
    for (int q = 0; q < 128; q += 4) {
        s0 += W1[(q + 0) * 128 + k] * W2[j * 128 + q + 0];
        s1 += W1[(q + 1) * 128 + k] * W2[j * 128 + q + 1];
        s2 += W1[(q + 2) * 128 + k] * W2[j * 128 + q + 2];
        s3 += W1[(q + 3) * 128 + k] * W2[j * 128 + q + 3];
    }
    T2[j * 128 + k] = (s0 + s1) + (s2 + s3);   // coalesced
}

// ---------------- pass 1: partition edges into 196 dst-bins (packed ints) ----------------
// blocks 0-31 additionally compute WcT[j][i] = sum_k W1[k][i] * T2[j][k]  (fused wprod2)

__global__ __launch_bounds__(256) void part_kernel(const void* __restrict__ edges,
                                                   const int* __restrict__ flag,
                                                   int* __restrict__ binned,
                                                   int* __restrict__ binCnt,
                                                   const float* __restrict__ W1,
                                                   const float* __restrict__ T2,
                                                   float* __restrict__ WcT) {
    __shared__ int hist[NB], base[NB], rank[NB];
    int t = threadIdx.x;
    for (int i = t; i < NB; i += 256) hist[i] = 0;
    __syncthreads();
    int i0 = blockIdx.x * 4096;
    bool is64 = (*flag != 0);
    int s[16], d[16];
    #pragma unroll
    for (int q = 0; q < 16; ++q) {
        int i = i0 + q * 256 + t;
        if (i < NE) {
            if (is64) {
                s[q] = (int)__builtin_nontemporal_load(&((const long long*)edges)[i]);
                d[q] = (int)__builtin_nontemporal_load(&((const long long*)edges)[NE + i]);
            } else {
                s[q] = __builtin_nontemporal_load(&((const int*)edges)[i]);
                d[q] = __builtin_nontemporal_load(&((const int*)edges)[NE + i]);
            }
            atomicAdd(&hist[d[q] >> 9], 1);
        } else d[q] = -1;
    }
    __syncthreads();
    for (int i = t; i < NB; i += 256) {
        base[i] = atomicAdd(&binCnt[i], hist[i]);
        rank[i] = 0;
    }
    __syncthreads();
    #pragma unroll
    for (int q = 0; q < 16; ++q) {
        if (d[q] >= 0) {
            int b = d[q] >> 9;
            int r = base[b] + atomicAdd(&rank[b], 1);
            if (r < BINCAP)
                binned[(size_t)b * BINCAP + r] = ((d[q] & 511) << 17) | s[q];
        }
    }
    // fused wprod2 tail (independent work, no barrier needed)
    if (blockIdx.x < 32) {
        int idx = blockIdx.x * 256 + t;    // [0, 8192)
        int i = idx & 127;                 // lane-contiguous
        int j = idx >> 7;                  // wave-uniform
        float s0 = 0.f, s1 = 0.f, s2 = 0.f, s3 = 0.f;
        #pragma unroll 4
        for (int k = 0; k < 128; k += 4) {
            s0 += W1[(k + 0) * 128 + i] * T2[j * 128 + k + 0];
            s1 += W1[(k + 1) * 128 + i] * T2[j * 128 + k + 1];
            s2 += W1[(k + 2) * 128 + i] * T2[j * 128 + k + 2];
            s3 += W1[(k + 3) * 128 + i] * T2[j * 128 + k + 3];
        }
        WcT[j * 128 + i] = (s0 + s1) + (s2 + s3);   // coalesced
    }
}

// ---------------- pass 2: per-bin degree hist -> dinv, rowoff, sorted CSR ----------------

__global__ __launch_bounds__(1024) void build2_kernel(const int* __restrict__ binCnt,
                                                      const int* __restrict__ binned,
                                                      float* __restrict__ dinv,
                                                      int* __restrict__ rowoff,
                                                      int* __restrict__ edge) {
    extern __shared__ char smem[];
    int* stage = (int*)smem;                        // BINCAP
    int* hist  = (int*)(smem + (size_t)BINCAP * 4); // 512
    int* sc    = hist + 512;                        // 512
    int* cur   = sc + 512;                          // 512
    int* bsc   = cur + 512;                         // 256
    int b = blockIdx.x, t = threadIdx.x;
    int nb0 = b << 9;
    int nNodes = min(512, NN - nb0);

    // local exclusive scan of (binCnt + nodes) to recover this bin's global offset
    if (t < 256) {
        int nodes = (t < NB) ? min(512, NN - (t << 9)) : 0;
        bsc[t] = (t < NB) ? binCnt[t] + nodes : 0;
    }
    if (t < 512) hist[t] = 0;
    __syncthreads();
    for (int off = 1; off < 256; off <<= 1) {
        int a = (t < 256 && t >= off) ? bsc[t - off] : 0;
        __syncthreads();
        if (t < 256) bsc[t] += a;
        __syncthreads();
    }
    int cntRaw = binCnt[b];
    int cnt = min(cntRaw, BINCAP);
    int off0 = bsc[b] - (cntRaw + nNodes);   // exclusive prefix

    const int* e = binned + (size_t)b * BINCAP;
    for (int i = t; i < cnt; i += 1024) atomicAdd(&hist[e[i] >> 17], 1);
    __syncthreads();
    int v = 0;
    if (t < 512) { v = (t < nNodes) ? hist[t] + 1 : 0; sc[t] = v; }
    __syncthreads();
    for (int off = 1; off < 512; off <<= 1) {
        int a = (t < 512 && t >= off) ? sc[t - off] : 0;
        __syncthreads();
        if (t < 512) sc[t] += a;
        __syncthreads();
    }
    if (t < nNodes) {
        dinv[nb0 + t] = rsqrtf((float)(hist[t] + 1));
        int lo = sc[t] - v;
        rowoff[nb0 + t] = off0 + lo;
        stage[lo] = nb0 + t;        // self loop first
        cur[t] = lo + 1;
    }
    if (b == NB - 1 && t == 0) rowoff[NN] = ENT;
    __syncthreads();
    for (int i = t; i < cnt; i += 1024) {
        int pk = e[i];
        int slot = atomicAdd(&cur[pk >> 17], 1);
        if (slot < BINCAP) stage[slot] = pk & 0x1FFFF;
    }
    __syncthreads();
    int total = min(cntRaw + nNodes, BINCAP);
    int* dst = edge + off0;
    for (int i = t; i < total; i += 1024) dst[i] = stage[i];
}

// ---------------- propagate (F=64): unweighted gather-sum + dinv^SPOW epilogue ----------------
// One wave per node, lane = feature. 16-deep gather (r7/r8 A/B: latency-bound to ~2KB
// in flight, then ~3.7 TB/s scattered-fetch ceiling — structural floor).

template<int SPOW>
__global__ __launch_bounds__(1024) void spmm64f_kernel(const int* __restrict__ rowoff,
                                                       const int* __restrict__ col,
                                                       const float* __restrict__ dinv,
                                                       const float* __restrict__ H,
                                                       float* __restrict__ O) {
    int w = (int)((blockIdx.x * 1024u + threadIdx.x) >> 6);
    if (w >= NN) return;
    int lane = threadIdx.x & 63;
    int s = __builtin_amdgcn_readfirstlane(rowoff[w]);
    int e = __builtin_amdgcn_readfirstlane(rowoff[w + 1]);
    float acc = 0.f;
    const float* base = H + lane;

    int p = s;
    for (; p + 16 <= e; p += 16) {
        int c[16];
        #pragma unroll
        for (int q = 0; q < 16; ++q) c[q] = __builtin_nontemporal_load(&col[p + q]);
        #pragma unroll
        for (int q = 0; q < 16; ++q) acc += base[(size_t)c[q] * 64];
    }
    if (p + 8 <= e) {
        int c[8];
        #pragma unroll
        for (int q = 0; q < 8; ++q) c[q] = __builtin_nontemporal_load(&col[p + q]);
        #pragma unroll
        for (int q = 0; q < 8; ++q) acc += base[(size_t)c[q] * 64];
        p += 8;
    }
    if (p + 4 <= e) {
        int c[4];
        #pragma unroll
        for (int q = 0; q < 4; ++q) c[q] = __builtin_nontemporal_load(&col[p + q]);
        #pragma unroll
        for (int q = 0; q < 4; ++q) acc += base[(size_t)c[q] * 64];
        p += 4;
    }
    for (; p < e; ++p) acc += base[(size_t)__builtin_nontemporal_load(&col[p]) * 64];

    float di = dinv[w];
    float scale = (SPOW == 2) ? di * di : di;
    __builtin_nontemporal_store(acc * scale, &O[(size_t)w * 64 + lane]);
}

// ---------------- fp32 GEMM: G[M,64] = dinv[m] * (X[M,128] @ W[64,128]^T) ----------------

__global__ __launch_bounds__(256) void gemm_xwt64_kernel(const float* __restrict__ X,
                                                         const float* __restrict__ W,
                                                         const float* __restrict__ dinv,
                                                         float* __restrict__ Y, int M) {
    constexpr int N = 64, K = 128, BM = 64, BK = 32;
    constexpr int TM = 4, TN = N / 16;
    __shared__ float Xs[BK][BM + 4];
    __shared__ float Ws[BK][N + 4];
    int t  = threadIdx.x;
    int m0 = blockIdx.x * BM;
    int r0 = (t >> 4) * TM;
    int c0 = (t & 15) * TN;
    float acc[TM][TN] = {};
    for (int k0 = 0; k0 < K; k0 += BK) {
        #pragma unroll
        for (int i = 0; i < 2; ++i) {            // X tile: 512 float4 (NT dwordx4)
            int f  = t + i * 256;
            int m  = f >> 3;
            int kq = (f & 7) << 2;
            int gm = m0 + m; if (gm >= M) gm = M - 1;
            f4v v = __builtin_nontemporal_load(
                (const f4v*)&X[(size_t)gm * K + k0 + kq]);
            Xs[kq + 0][m] = v.x; Xs[kq + 1][m] = v.y;
            Xs[kq + 2][m] = v.z; Xs[kq + 3][m] = v.w;
        }
        #pragma unroll
        for (int i = 0; i < N / 32; ++i) {       // W tile
            int f  = t + i * 256;
            int n  = f >> 3;
            int kq = (f & 7) << 2;
            float4 v = *(const float4*)&W[(size_t)n * K + k0 + kq];
            Ws[kq + 0][n] = v.x; Ws[kq + 1][n] = v.y;
            Ws[kq + 2][n] = v.z; Ws[kq + 3][n] = v.w;
        }
        __syncthreads();
        #pragma unroll
        for (int k = 0; k < BK; ++k) {
            float4 xv = *(const float4*)&Xs[k][r0];
            float xf[TM] = {xv.x, xv.y, xv.z, xv.w};
            float wf[TN];
            #pragma unroll
            for (int j = 0; j < TN; j += 4) {
                float4 wv = *(const float4*)&Ws[k][c0 + j];
                wf[j] = wv.x; wf[j + 1] = wv.y; wf[j + 2] = wv.z; wf[j + 3] = wv.w;
            }
            #pragma unroll
            for (int i = 0; i < TM; ++i)
                #pragma unroll
                for (int j = 0; j < TN; ++j)
                    acc[i][j] += xf[i] * wf[j];
        }
        __syncthreads();
    }
    #pragma unroll
    for (int i = 0; i < TM; ++i) {
        int gm = m0 + r0 + i;
        if (gm < M) {
            float di = dinv[gm];
            #pragma unroll
            for (int j = 0; j < TN; j += 4) {
                f4v v = {di * acc[i][j], di * acc[i][j + 1],
                         di * acc[i][j + 2], di * acc[i][j + 3]};
                __builtin_nontemporal_store(v, (f4v*)&Y[(size_t)gm * N + c0 + j]);
            }
        }
    }
}

// ---------------- launch ----------------

extern "C" void kernel_launch(void* const* d_in, const int* in_sizes, int n_in,
                              void* d_out, int out_size, void* d_ws, size_t ws_size,
                              hipStream_t stream) {
    const float* x     = (const float*)d_in[0];
    const void*  edges = d_in[1];
    const float* W1    = (const float*)d_in[2];
    const float* W2    = (const float*)d_in[3];
    float* out = (float*)d_out;

    char* ws = (char*)d_ws;
    size_t off = 0;
    auto take = [&](size_t bytes) -> char* {
        char* p = ws + off;
        off = (off + bytes + 255) & ~(size_t)255;
        return p;
    };
    int*   flag   = (int*)take(4);
    int*   binCnt = (int*)take((size_t)NB * 4);
    float* dinv   = (float*)take((size_t)NN * 4);
    int*   rowoff = (int*)take((size_t)(NN + 1) * 4);
    float* T2     = (float*)take((size_t)64 * 128 * 4);
    float* WcT    = (float*)take((size_t)64 * 128 * 4);
    int*   binned = (int*)take((size_t)NB * BINCAP * 4);
    int*   edgeA  = (int*)take((size_t)ENT * 4);
    float* g      = (float*)take((size_t)NN * 64 * 4);
    float* y      = (float*)take((size_t)NN * 64 * 4);
    if (off > ws_size) return;   // workspace too small: fail cleanly

    // --- build: weights(+probe/zero), partition(+wprod2), per-bin CSR ---
    wprod1_kernel<<<32, 256, 0, stream>>>(W1, W2, T2, (const unsigned*)edges, flag, binCnt);
    part_kernel<<<(NE + 4095) / 4096, 256, 0, stream>>>(edges, flag, binned, binCnt,
                                                        W1, T2, WcT);
    size_t b2lds = (size_t)BINCAP * 4 + (512 * 3 + 256) * 4;
    build2_kernel<<<NB, 1024, b2lds, stream>>>(binCnt, binned, dinv, rowoff, edgeA);

    // --- collapsed network: out = D^-1/2 Ab D^-1 Ab D^-1 Ab D^-1/2 (X Wc) ---
    const int GB = (NN + 63) / 64;            // 1563
    const int PB = (NN * 64 + 1023) / 1024;   // 6250 (16 node-waves per block)

    gemm_xwt64_kernel<<<GB, 256, 0, stream>>>(x, WcT, dinv, g, NN);
    spmm64f_kernel<2><<<PB, 1024, 0, stream>>>(rowoff, edgeA, dinv, g, y);
    spmm64f_kernel<2><<<PB, 1024, 0, stream>>>(rowoff, edgeA, dinv, y, g);
    spmm64f_kernel<1><<<PB, 1024, 0, stream>>>(rowoff, edgeA, dinv, g, out);
}

// Round 11
// 250.297 us; speedup vs baseline: 1.0320x; 1.0320x over previous
//
#include <hip/hip_runtime.h>

#define NN 100000
#define NE 1600000
#define ENT (NE + NN)      // edges + self loops
#define NB 196             // bins of 512 dst nodes (dst >> 9)
#define BINCAP 10240       // slab capacity per bin (mean 8192+512, +17 sigma)

typedef float f4v __attribute__((ext_vector_type(4)));   // NT-builtin-compatible

// ---------------- collapsed weights step 1 + (block 0) probe/zero setup ----------------
// T2[j][k] = sum_q W1[q][k] * W2[j][q]      (T = W1^T W2^T, stored transposed [64][128])
// lane-varying index k is contiguous in all vector accesses; j is wave-uniform.

__global__ __launch_bounds__(256) void wprod1_kernel(const float* __restrict__ W1,
                                                     const float* __restrict__ W2,
                                                     float* __restrict__ T2,
                                                     const unsigned* __restrict__ edges,
                                                     int* __restrict__ flag,
                                                     int* __restrict__ binCnt) {
    if (blockIdx.x == 0) {                 // fused setup
        int t = threadIdx.x;
        if (t < NB) binCnt[t] = 0;
        if (t == 0) {
            int is64 = 1;
            for (int i = 1; i < 64; i += 2)
                if (edges[i] != 0u) { is64 = 0; break; }
            *flag = is64;
        }
    }
    int idx = blockIdx.x * blockDim.x + threadIdx.x;   // [0, 8192)
    int k = idx & 127;            // lane-contiguous
    int j = idx >> 7;             // wave-uniform
    float s0 = 0.f, s1 = 0.f, s2 = 0.f, s3 = 0.f;
    #pragma unroll 4
    for (int q = 0; q < 128; q += 4) {
        s0 += W1[(q + 0) * 128 + k] * W2[j * 128 + q + 0];
        s1 += W1[(q + 1) * 128 + k] * W2[j * 128 + q + 1];
        s2 += W1[(q + 2) * 128 + k] * W2[j * 128 + q + 2];
        s3 += W1[(q + 3) * 128 + k] * W2[j * 128 + q + 3];
    }
    T2[j * 128 + k] = (s0 + s1) + (s2 + s3);   // coalesced
}

// ---------------- pass 1: partition edges into 196 dst-bins (packed ints) ----------------
// blocks 0-31 additionally compute WcT[j][i] = sum_k W1[k][i] * T2[j][k]  (fused wprod2)

__global__ __launch_bounds__(256) void part_kernel(const void* __restrict__ edges,
                                                   const int* __restrict__ flag,
                                                   int* __restrict__ binned,
                                                   int* __restrict__ binCnt,
                                                   const float* __restrict__ W1,
                                                   const float* __restrict__ T2,
                                                   float* __restrict__ WcT) {
    __shared__ int hist[NB], base[NB], rank[NB];
    int t = threadIdx.x;
    for (int i = t; i < NB; i += 256) hist[i] = 0;
    __syncthreads();
    int i0 = blockIdx.x * 4096;
    bool is64 = (*flag != 0);
    int s[16], d[16];
    #pragma unroll
    for (int q = 0; q < 16; ++q) {
        int i = i0 + q * 256 + t;
        if (i < NE) {
            if (is64) {
                s[q] = (int)__builtin_nontemporal_load(&((const long long*)edges)[i]);
                d[q] = (int)__builtin_nontemporal_load(&((const long long*)edges)[NE + i]);
            } else {
                s[q] = __builtin_nontemporal_load(&((const int*)edges)[i]);
                d[q] = __builtin_nontemporal_load(&((const int*)edges)[NE + i]);
            }
            atomicAdd(&hist[d[q] >> 9], 1);
        } else d[q] = -1;
    }
    __syncthreads();
    for (int i = t; i < NB; i += 256) {
        base[i] = atomicAdd(&binCnt[i], hist[i]);
        rank[i] = 0;
    }
    __syncthreads();
    #pragma unroll
    for (int q = 0; q < 16; ++q) {
        if (d[q] >= 0) {
            int b = d[q] >> 9;
            int r = base[b] + atomicAdd(&rank[b], 1);
            if (r < BINCAP)
                binned[(size_t)b * BINCAP + r] = ((d[q] & 511) << 17) | s[q];
        }
    }
    // fused wprod2 tail (independent work, no barrier needed)
    if (blockIdx.x < 32) {
        int idx = blockIdx.x * 256 + t;    // [0, 8192)
        int i = idx & 127;                 // lane-contiguous
        int j = idx >> 7;                  // wave-uniform
        float s0 = 0.f, s1 = 0.f, s2 = 0.f, s3 = 0.f;
        #pragma unroll 4
        for (int k = 0; k < 128; k += 4) {
            s0 += W1[(k + 0) * 128 + i] * T2[j * 128 + k + 0];
            s1 += W1[(k + 1) * 128 + i] * T2[j * 128 + k + 1];
            s2 += W1[(k + 2) * 128 + i] * T2[j * 128 + k + 2];
            s3 += W1[(k + 3) * 128 + i] * T2[j * 128 + k + 3];
        }
        WcT[j * 128 + i] = (s0 + s1) + (s2 + s3);   // coalesced
    }
}

// ---------------- pass 2: per-bin degree hist -> dinv, rowoff, sorted CSR ----------------

__global__ __launch_bounds__(1024) void build2_kernel(const int* __restrict__ binCnt,
                                                      const int* __restrict__ binned,
                                                      float* __restrict__ dinv,
                                                      int* __restrict__ rowoff,
                                                      int* __restrict__ edge) {
    extern __shared__ char smem[];
    int* stage = (int*)smem;                        // BINCAP
    int* hist  = (int*)(smem + (size_t)BINCAP * 4); // 512
    int* sc    = hist + 512;                        // 512
    int* cur   = sc + 512;                          // 512
    int* bsc   = cur + 512;                         // 256
    int b = blockIdx.x, t = threadIdx.x;
    int nb0 = b << 9;
    int nNodes = min(512, NN - nb0);

    // local exclusive scan of (binCnt + nodes) to recover this bin's global offset
    if (t < 256) {
        int nodes = (t < NB) ? min(512, NN - (t << 9)) : 0;
        bsc[t] = (t < NB) ? binCnt[t] + nodes : 0;
    }
    if (t < 512) hist[t] = 0;
    __syncthreads();
    for (int off = 1; off < 256; off <<= 1) {
        int a = (t < 256 && t >= off) ? bsc[t - off] : 0;
        __syncthreads();
        if (t < 256) bsc[t] += a;
        __syncthreads();
    }
    int cntRaw = binCnt[b];
    int cnt = min(cntRaw, BINCAP);
    int off0 = bsc[b] - (cntRaw + nNodes);   // exclusive prefix

    const int* e = binned + (size_t)b * BINCAP;
    for (int i = t; i < cnt; i += 1024) atomicAdd(&hist[e[i] >> 17], 1);
    __syncthreads();
    int v = 0;
    if (t < 512) { v = (t < nNodes) ? hist[t] + 1 : 0; sc[t] = v; }
    __syncthreads();
    for (int off = 1; off < 512; off <<= 1) {
        int a = (t < 512 && t >= off) ? sc[t - off] : 0;
        __syncthreads();
        if (t < 512) sc[t] += a;
        __syncthreads();
    }
    if (t < nNodes) {
        dinv[nb0 + t] = rsqrtf((float)(hist[t] + 1));
        int lo = sc[t] - v;
        rowoff[nb0 + t] = off0 + lo;
        stage[lo] = nb0 + t;        // self loop first
        cur[t] = lo + 1;
    }
    if (b == NB - 1 && t == 0) rowoff[NN] = ENT;
    __syncthreads();
    for (int i = t; i < cnt; i += 1024) {
        int pk = e[i];
        int slot = atomicAdd(&cur[pk >> 17], 1);
        if (slot < BINCAP) stage[slot] = pk & 0x1FFFF;
    }
    __syncthreads();
    int total = min(cntRaw + nNodes, BINCAP);
    int* dst = edge + off0;
    for (int i = t; i < total; i += 1024) dst[i] = stage[i];
}

// ---------------- propagate (F=64): unweighted gather-sum + dinv^SPOW epilogue ----------------
// One wave per node, lane = feature, 256-thread blocks (r10 A/B: 1024-blocks cost
// ~9% occupancy). 16-deep gather; ~3.7 TB/s scattered-fetch ceiling = structural floor.

template<int SPOW>
__global__ __launch_bounds__(256, 8) void spmm64f_kernel(const int* __restrict__ rowoff,
                                                         const int* __restrict__ col,
                                                         const float* __restrict__ dinv,
                                                         const float* __restrict__ H,
                                                         float* __restrict__ O) {
    int w = (int)((blockIdx.x * 256u + threadIdx.x) >> 6);
    if (w >= NN) return;
    int lane = threadIdx.x & 63;
    int s = __builtin_amdgcn_readfirstlane(rowoff[w]);
    int e = __builtin_amdgcn_readfirstlane(rowoff[w + 1]);
    float acc = 0.f;
    const float* base = H + lane;

    int p = s;
    for (; p + 16 <= e; p += 16) {
        int c[16];
        #pragma unroll
        for (int q = 0; q < 16; ++q) c[q] = __builtin_nontemporal_load(&col[p + q]);
        #pragma unroll
        for (int q = 0; q < 16; ++q) acc += base[(size_t)c[q] * 64];
    }
    if (p + 8 <= e) {
        int c[8];
        #pragma unroll
        for (int q = 0; q < 8; ++q) c[q] = __builtin_nontemporal_load(&col[p + q]);
        #pragma unroll
        for (int q = 0; q < 8; ++q) acc += base[(size_t)c[q] * 64];
        p += 8;
    }
    if (p + 4 <= e) {
        int c[4];
        #pragma unroll
        for (int q = 0; q < 4; ++q) c[q] = __builtin_nontemporal_load(&col[p + q]);
        #pragma unroll
        for (int q = 0; q < 4; ++q) acc += base[(size_t)c[q] * 64];
        p += 4;
    }
    for (; p < e; ++p) acc += base[(size_t)__builtin_nontemporal_load(&col[p]) * 64];

    float di = dinv[w];
    float scale = (SPOW == 2) ? di * di : di;
    __builtin_nontemporal_store(acc * scale, &O[(size_t)w * 64 + lane]);
}

// ---------------- fp32 GEMM: G[M,64] = dinv[m] * (X[M,128] @ W[64,128]^T) ----------------

__global__ __launch_bounds__(256) void gemm_xwt64_kernel(const float* __restrict__ X,
                                                         const float* __restrict__ W,
                                                         const float* __restrict__ dinv,
                                                         float* __restrict__ Y, int M) {
    constexpr int N = 64, K = 128, BM = 64, BK = 32;
    constexpr int TM = 4, TN = N / 16;
    __shared__ float Xs[BK][BM + 4];
    __shared__ float Ws[BK][N + 4];
    int t  = threadIdx.x;
    int m0 = blockIdx.x * BM;
    int r0 = (t >> 4) * TM;
    int c0 = (t & 15) * TN;
    float acc[TM][TN] = {};
    for (int k0 = 0; k0 < K; k0 += BK) {
        #pragma unroll
        for (int i = 0; i < 2; ++i) {            // X tile: 512 float4 (NT dwordx4)
            int f  = t + i * 256;
            int m  = f >> 3;
            int kq = (f & 7) << 2;
            int gm = m0 + m; if (gm >= M) gm = M - 1;
            f4v v = __builtin_nontemporal_load(
                (const f4v*)&X[(size_t)gm * K + k0 + kq]);
            Xs[kq + 0][m] = v.x; Xs[kq + 1][m] = v.y;
            Xs[kq + 2][m] = v.z; Xs[kq + 3][m] = v.w;
        }
        #pragma unroll
        for (int i = 0; i < N / 32; ++i) {       // W tile
            int f  = t + i * 256;
            int n  = f >> 3;
            int kq = (f & 7) << 2;
            float4 v = *(const float4*)&W[(size_t)n * K + k0 + kq];
            Ws[kq + 0][n] = v.x; Ws[kq + 1][n] = v.y;
            Ws[kq + 2][n] = v.z; Ws[kq + 3][n] = v.w;
        }
        __syncthreads();
        #pragma unroll
        for (int k = 0; k < BK; ++k) {
            float4 xv = *(const float4*)&Xs[k][r0];
            float xf[TM] = {xv.x, xv.y, xv.z, xv.w};
            float wf[TN];
            #pragma unroll
            for (int j = 0; j < TN; j += 4) {
                float4 wv = *(const float4*)&Ws[k][c0 + j];
                wf[j] = wv.x; wf[j + 1] = wv.y; wf[j + 2] = wv.z; wf[j + 3] = wv.w;
            }
            #pragma unroll
            for (int i = 0; i < TM; ++i)
                #pragma unroll
                for (int j = 0; j < TN; ++j)
                    acc[i][j] += xf[i] * wf[j];
        }
        __syncthreads();
    }
    #pragma unroll
    for (int i = 0; i < TM; ++i) {
        int gm = m0 + r0 + i;
        if (gm < M) {
            float di = dinv[gm];
            #pragma unroll
            for (int j = 0; j < TN; j += 4) {
                f4v v = {di * acc[i][j], di * acc[i][j + 1],
                         di * acc[i][j + 2], di * acc[i][j + 3]};
                __builtin_nontemporal_store(v, (f4v*)&Y[(size_t)gm * N + c0 + j]);
            }
        }
    }
}

// ---------------- launch ----------------

extern "C" void kernel_launch(void* const* d_in, const int* in_sizes, int n_in,
                              void* d_out, int out_size, void* d_ws, size_t ws_size,
                              hipStream_t stream) {
    const float* x     = (const float*)d_in[0];
    const void*  edges = d_in[1];
    const float* W1    = (const float*)d_in[2];
    const float* W2    = (const float*)d_in[3];
    float* out = (float*)d_out;

    char* ws = (char*)d_ws;
    size_t off = 0;
    auto take = [&](size_t bytes) -> char* {
        char* p = ws + off;
        off = (off + bytes + 255) & ~(size_t)255;
        return p;
    };
    int*   flag   = (int*)take(4);
    int*   binCnt = (int*)take((size_t)NB * 4);
    float* dinv   = (float*)take((size_t)NN * 4);
    int*   rowoff = (int*)take((size_t)(NN + 1) * 4);
    float* T2     = (float*)take((size_t)64 * 128 * 4);
    float* WcT    = (float*)take((size_t)64 * 128 * 4);
    int*   binned = (int*)take((size_t)NB * BINCAP * 4);
    int*   edgeA  = (int*)take((size_t)ENT * 4);
    float* g      = (float*)take((size_t)NN * 64 * 4);
    float* y      = (float*)take((size_t)NN * 64 * 4);
    if (off > ws_size) return;   // workspace too small: fail cleanly

    // --- build: weights(+probe/zero), partition(+wprod2), per-bin CSR ---
    wprod1_kernel<<<32, 256, 0, stream>>>(W1, W2, T2, (const unsigned*)edges, flag, binCnt);
    part_kernel<<<(NE + 4095) / 4096, 256, 0, stream>>>(edges, flag, binned, binCnt,
                                                        W1, T2, WcT);
    size_t b2lds = (size_t)BINCAP * 4 + (512 * 3 + 256) * 4;
    build2_kernel<<<NB, 1024, b2lds, stream>>>(binCnt, binned, dinv, rowoff, edgeA);

    // --- collapsed network: out = D^-1/2 Ab D^-1 Ab D^-1 Ab D^-1/2 (X Wc) ---
    const int GB = (NN + 63) / 64;          // 1563
    const int PB = (NN * 64 + 255) / 256;   // 25000 (one wave per node)

    gemm_xwt64_kernel<<<GB, 256, 0, stream>>>(x, WcT, dinv, g, NN);
    spmm64f_kernel<2><<<PB, 256, 0, stream>>>(rowoff, edgeA, dinv, g, y);
    spmm64f_kernel<2><<<PB, 256, 0, stream>>>(rowoff, edgeA, dinv, y, g);
    spmm64f_kernel<1><<<PB, 256, 0, stream>>>(rowoff, edgeA, dinv, g, out);
}